// Round 4
// baseline (401.879 us; speedup 1.0000x reference)
//
#include <hip/hip_runtime.h>

// SNN forward scan: B=64, N=1024, T=512. Row = (b*N+n), x[row*512 + t].
//
// R11: 2-deep load pipeline on the R8 base (R9/R10 DRAM-pattern attacks
// both falsified; regression over R8+R10 gives T = 6.6us/phase FIXED +
// 33us data -> data component already runs ~6.1 TB/s; the limiter is a
// per-phase fixed cost). Theory: exposed read latency at stage()'s vmcnt
// wait. R8's pipeline is 1 chunk deep: chunk k+1's 16 loads issue in
// phase k and are waited at phase k+1's stage with only phase-B's ~1us
// of slack; under whole-grid congestion a block's 16-KiB read burst takes
// ~5.4us fair-share service time -> the block idles at the wait, every
// phase. Fix: double register buffer (ldA/ldB). Chunk c issues TWO phases
// before its stage; compiler emits s_waitcnt vmcnt(16) (older chunk
// waited, newer still in flight) -> ~2 phases (>10us) of slack covers the
// congested latency. Store wave's NT stores are on a different wave ->
// separate vmcnt, no interference. Macros bind reg arrays statically (no
// runtime indexing -> no scratch). __launch_bounds__(192,3) caps VGPR at
// ~170 to hold 3 blocks/CU. Everything else identical to R8 -> bit-exact.
// Predicted: FETCH/WRITE/conflicts unchanged; VGPR ~160; dur 85.7 ->
// 55-70us if theory right; 80-90us falsifies -> pivot to global_load_lds
// 3-buffer in-place design.
//
// Numerics: BIT-EXACT vs float32 NumPy reference (0/1 threshold output —
// one ulp flip cascades). __fmul_rn/__fadd_rn + contract(off).
#pragma clang fp contract(off)

#define ROWS    64                    // rows per block (1 compute wave)
#define T_LEN   512
#define CHUNK   64                    // timesteps per tile (256 B/row contiguous)
#define NCHUNK  (T_LEN / CHUNK)       // 8
#define STRIDE  (CHUNK + 1)           // 65: odd -> conflict-free b32 LDS
#define NV      16                    // float4 per io-lane per chunk
#define NPARAM  1024

typedef float f4_nt __attribute__((ext_vector_type(4)));

// lgkmcnt(0)-only barrier: LDS visibility without the vmcnt(0) drain.
#define BARRIER() asm volatile("s_waitcnt lgkmcnt(0)\n\ts_barrier" ::: "memory")

__global__ __launch_bounds__(192, 3) void snn_fwd(
    const float* __restrict__ x,
    const float* __restrict__ beta,
    const float* __restrict__ p,
    const float* __restrict__ bparam,
    float* __restrict__ out)
{
    __shared__ float inbuf[2][ROWS * STRIDE];  // 2 x 16,640 B
    __shared__ float outbuf[ROWS * STRIDE];    //     16,640 B  (49.9 KB total)

    const int tid     = threadIdx.x;
    const int wid     = tid >> 6;       // 0=compute, 1=load, 2=store
    const int lane    = tid & 63;
    const int rowBase = blockIdx.x * ROWS;

    const float4* __restrict__ xv = (const float4*)x;  // row stride 128 float4
    float4* __restrict__ ov       = (float4*)out;

    // io mapping: lane = r4*16 + t16. One instr: rows {r4+4*it}, 16 float4
    // (=256 B) contiguous per row. Chunk k adds k*NV float4.
    const int t16 = lane & 15;
    const int r4  = lane >> 4;
    const int gq  = (rowBase + r4) * (T_LEN / 4) + t16;  // float4 units
    const int lf  = r4 * STRIDE + t16 * 4;               // float units

    // compute state
    float mem = 0.0f, refac = 2.0f, a = 0.0f, vth = 1.0f, ps = 0.0f;
    float beta_c = 0.f, p_c = 0.f, b_c = 0.f;
    const int cb = lane * STRIDE;  // compute lane's LDS row

    if (wid == 0) {
        const int n = (rowBase + lane) & (NPARAM - 1);
        beta_c = fminf(fmaxf(beta[n], 0.001f), 0.999f);
        p_c    = fminf(fabsf(p[n]), 0.999f);
        b_c    = fminf(fmaxf(fabsf(bparam[n]), 0.001f), 1.0f);
    }

    auto step = [&](float xt) -> float {
        refac = (ps > 0.0f) ? 0.0f : refac;           // spike-triggered reset
        const float ic = (refac < 2.0f) ? 0.0f : xt;  // refractory input mask
        refac += 1.0f;
        const float nm   = __fadd_rn(__fmul_rn(mem, beta_c), ic);  // integrate
        const float diff = __fsub_rn(nm, vth);
        const float s    = (diff > 0.0f) ? 1.0f : 0.0f;
        mem = (diff > 0.0f) ? 0.0f : nm;              // reset-to-zero on spike
        a   = __fadd_rn(__fmul_rn(p_c, a), s);        // adaptation
        vth = __fadd_rn(1.0f, __fmul_rn(b_c, a));     // adaptive threshold
        ps  = s;
        return s;
    };

    float4 ldA[NV], ldB[NV];  // 2-deep register pipeline (2 chunks in flight)

// issue chunk kc's 16 loads into register buffer ldS (macro: static binding)
#define LOADCHUNK(kc, ldS)                                        \
    {                                                             \
        const int base_ = gq + (kc) * NV;                         \
        _Pragma("unroll")                                         \
        for (int it = 0; it < NV; ++it)                           \
            ldS[it] = xv[base_ + it * 4 * (T_LEN / 4)];           \
    }

// b32 scatter of ldS into inbuf[buf_] ([row][65] layout). Reading ldS here
// makes the compiler emit a counted vmcnt (newer chunk stays in flight).
#define STAGE(buf_, ldS)                                          \
    {                                                             \
        _Pragma("unroll")                                         \
        for (int it = 0; it < NV; ++it) {                         \
            const int o_ = lf + it * 4 * STRIDE;                  \
            inbuf[buf_][o_ + 0] = ldS[it].x;                      \
            inbuf[buf_][o_ + 1] = ldS[it].y;                      \
            inbuf[buf_][o_ + 2] = ldS[it].z;                      \
            inbuf[buf_][o_ + 3] = ldS[it].w;                      \
        }                                                         \
    }

    auto drain = [&](int k) {     // outbuf -> global, 256 B/row contiguous, NT
        const int base = gq + k * NV;
        #pragma unroll
        for (int it = 0; it < NV; ++it) {
            const int o = lf + it * 4 * STRIDE;
            float4 sv;
            sv.x = outbuf[o + 0];
            sv.y = outbuf[o + 1];
            sv.z = outbuf[o + 2];
            sv.w = outbuf[o + 3];
            __builtin_nontemporal_store(
                *reinterpret_cast<f4_nt*>(&sv),
                reinterpret_cast<f4_nt*>(&ov[base + it * 4 * (T_LEN / 4)]));
        }
    };

// one chunk-phase: compute k | stage k+1 (from LDS_) + issue k+3 (into LDS_)
// | drain k-1; then publish spikes(k) to outbuf.
#define PHASE(kk_, LDS_)                                          \
    {                                                             \
        const int k   = (kk_);                                    \
        const int cur = k & 1;                                    \
        float sv[CHUNK];                                          \
        if (wid == 0) {                                           \
            _Pragma("unroll")                                     \
            for (int t = 0; t < CHUNK; ++t)                       \
                sv[t] = step(inbuf[cur][cb + t]);                 \
        } else if (wid == 1) {                                    \
            if (k + 1 < NCHUNK) STAGE(cur ^ 1, LDS_);             \
            if (k + 3 < NCHUNK) LOADCHUNK(k + 3, LDS_);           \
        } else {                                                  \
            if (k > 0) drain(k - 1);                              \
        }                                                         \
        BARRIER();  /* outbuf reads done; inbuf[cur^1] staged */  \
        if (wid == 0) {                                           \
            _Pragma("unroll")                                     \
            for (int t = 0; t < CHUNK; ++t)                       \
                outbuf[cb + t] = sv[t];                           \
        }                                                         \
        BARRIER();  /* outbuf[k] visible to store wave */         \
    }

    // preamble: chunk 0 staged; chunks 1 (ldB) and 2 (ldA) in flight
    if (wid == 1) {
        LOADCHUNK(0, ldA);
        STAGE(0, ldA);
        LOADCHUNK(1, ldB);
        LOADCHUNK(2, ldA);
    }
    BARRIER();

    // chunk c staged from: c odd -> ldB, c even -> ldA  (stage at phase c-1)
    #pragma unroll 1
    for (int kk = 0; kk < NCHUNK; kk += 2) {
        PHASE(kk,     ldB);   // stage odd chunk k+1, reload ldB with k+3
        PHASE(kk + 1, ldA);   // stage even chunk k+1, reload ldA with k+3
    }
    if (wid == 2) drain(NCHUNK - 1);
}

extern "C" void kernel_launch(void* const* d_in, const int* in_sizes, int n_in,
                              void* d_out, int out_size, void* d_ws, size_t ws_size,
                              hipStream_t stream) {
    const float* x    = (const float*)d_in[0];
    const float* beta = (const float*)d_in[1];
    const float* p    = (const float*)d_in[2];
    const float* b    = (const float*)d_in[3];
    float* out        = (float*)d_out;

    const int BN = 64 * 1024;  // rows
    snn_fwd<<<dim3(BN / ROWS), dim3(192), 0, stream>>>(x, beta, p, b, out);
}

// Round 5
// 247.886 us; speedup vs baseline: 1.6212x; 1.6212x over previous
//
#include <hip/hip_runtime.h>

// SNN forward scan: B=64, N=1024, T=512. Row = (b*N+n), x[row*512 + t].
//
// R12: async DMA staging via __builtin_amdgcn_global_load_lds (16 B), 3
// rotating un-padded inbufs, counted s_waitcnt vmcnt(16). R11's register
// pipeline spilled (VGPR 84 + 178 MB scratch writes) and never tested the
// latency theory; this version removes BOTH io-path serialization (no
// stage step at all: DMA writes LDS directly, io wave = 16 issue instrs +
// 1 counted wait with ~2 phases in flight) AND compute-side LDS overhead
// (64 b32 reads -> 16 ds_read_b128) with ZERO register arrays alive
// across barriers -> no spill risk.
//
// Swizzle (G21 both-sides-or-neither): global_load_lds writes lane-linear
// LDS (base + lane*16). Lane i of instr it loads granule t16 ^ sw of its
// row, sw = r4 | ((it&1)<<2)  (same per-wave address set -> same
// coalescing). Compute reads granule g of row L at slot g ^ swl(L),
// swl = (L&3) | (((L>>2)&1)<<2) -> bank-quads evenly spread (8 lanes per
// quad = b128 optimum). Verified mapping: data(row L, granule g) lands at
// float4 index L*16 + (g ^ swl(L)).
//
// Spikes bit-packed (2x uint32/lane) -> outbuf = 1 KiB; store wave
// expands bits to float4 NT stores at identity addresses. LDS = 3*16384
// + 1024 = 50176 B (= R8) -> 3 blocks/CU.
//
// Schedule: phase k: A) compute chunk k from inbuf[k%3] | store drains
// bits(k-1); MID barrier; B) compute publishes bits(k) | io issues chunk
// k+2 into inbuf[(k+2)%3] then waits vmcnt(16) (chunk k+1 landed, k+2
// still flying; vmcnt(0) when nothing newer in flight); END barrier.
// io wave issues with vmcnt(0)-drain NEVER in the main loop (T4).
//
// Predicted: FETCH/WRITE unchanged; BANK_CONFLICT 2.1M -> ~0; VGPR
// 64-100; dur 85.7 -> 50-65 us if io/LDS serialization theory right;
// 80-90 us = pattern-BW cap confirmed -> attack pattern next or stop.
//
// Numerics: BIT-EXACT vs float32 reference (identical op order; spike
// storage as bits reproduces exact 0.0f/1.0f). contract(off).
#pragma clang fp contract(off)

#define ROWS    64                    // rows per block (1 compute wave)
#define T_LEN   512
#define CHUNK   64                    // timesteps per tile
#define NCHUNK  (T_LEN / CHUNK)       // 8
#define NV      16                    // float4 granules per row per chunk
#define BUFW    (ROWS * CHUNK)        // 4096 floats per inbuf (16 KiB)
#define NPARAM  1024

typedef float f4_nt __attribute__((ext_vector_type(4)));

// lgkmcnt(0)-only barrier: LDS visibility without the vmcnt(0) drain.
#define BARRIER() asm volatile("s_waitcnt lgkmcnt(0)\n\ts_barrier" ::: "memory")

// async global->LDS DMA, 16 B per lane: LDS dest = uniform base + lane*16
#define GLOAD16(gp, lp)                                                \
    __builtin_amdgcn_global_load_lds(                                  \
        (const __attribute__((address_space(1))) void*)(gp),           \
        (__attribute__((address_space(3))) void*)(lp), 16, 0, 0)

__global__ __launch_bounds__(192) void snn_fwd(
    const float* __restrict__ x,
    const float* __restrict__ beta,
    const float* __restrict__ p,
    const float* __restrict__ bparam,
    float* __restrict__ out)
{
    __shared__ __align__(16) float inbuf[3][BUFW];   // 3 x 16384 B, linear
    __shared__ __align__(16) unsigned int outw[ROWS][4];  // 1024 B (bits)

    const int tid     = threadIdx.x;
    const int wid     = tid >> 6;       // 0=compute, 1=load-issue, 2=store
    const int lane    = tid & 63;
    const int rowBase = blockIdx.x * ROWS;

    const float4* __restrict__ xv = (const float4*)x;  // row stride 128 float4
    float4* __restrict__ ov       = (float4*)out;

    // io lane decomposition: lane = r4*16 + t16; instr it covers rows r4+4*it
    const int t16 = lane & 15;
    const int r4  = lane >> 4;
    // load wave: pre-swizzled global granule (even/odd it differ by ^4)
    const int gEven = (rowBase + r4) * (T_LEN / 4) + (t16 ^ r4);
    const int gOdd  = gEven ^ 4;   // (t16^r4)^4 only flips bit2 of granule
    // store wave: identity mapping
    const int gq = (rowBase + r4) * (T_LEN / 4) + t16;

    // compute state
    float mem = 0.0f, refac = 2.0f, a = 0.0f, vth = 1.0f, ps = 0.0f;
    float beta_c = 0.f, p_c = 0.f, b_c = 0.f;
    const int swl   = (lane & 3) | (((lane >> 2) & 1) << 2);  // read swizzle
    const int cbase = lane * NV;                              // float4 units

    if (wid == 0) {
        const int n = (rowBase + lane) & (NPARAM - 1);
        beta_c = fminf(fmaxf(beta[n], 0.001f), 0.999f);
        p_c    = fminf(fabsf(p[n]), 0.999f);
        b_c    = fminf(fmaxf(fabsf(bparam[n]), 0.001f), 1.0f);
    }

    unsigned int b0 = 0, b1 = 0;   // bit-packed spikes for current chunk

    auto step = [&](float xt, unsigned int msk, unsigned int& bw) {
        refac = (ps > 0.0f) ? 0.0f : refac;           // spike-triggered reset
        const float ic = (refac < 2.0f) ? 0.0f : xt;  // refractory input mask
        refac += 1.0f;
        const float nm   = __fadd_rn(__fmul_rn(mem, beta_c), ic);  // integrate
        const float diff = __fsub_rn(nm, vth);
        const bool  sp   = diff > 0.0f;
        const float s    = sp ? 1.0f : 0.0f;
        bw |= sp ? msk : 0u;                          // side-chain, off chain
        mem = sp ? 0.0f : nm;                         // reset-to-zero on spike
        a   = __fadd_rn(__fmul_rn(p_c, a), s);        // adaptation
        vth = __fadd_rn(1.0f, __fmul_rn(b_c, a));     // adaptive threshold
        ps  = s;
    };

    // io wave: issue chunk c's 16 DMA loads into inbuf[buf] (no registers)
    auto issue = [&](int c, int buf) {
        float* lb = &inbuf[buf][0];
        #pragma unroll
        for (int it = 0; it < NV; ++it) {
            const int gidx = ((it & 1) ? gOdd : gEven)
                           + it * 4 * (T_LEN / 4) + c * NV;
            GLOAD16(&xv[gidx], lb + it * 256);   // lane-linear 1 KiB region
        }
    };

    // store wave: expand bits(chunk c) -> float4 NT stores (identity addr)
    auto drain = [&](int c) {
        #pragma unroll
        for (int it = 0; it < NV; ++it) {
            const int row = r4 + 4 * it;
            const uint2 bits = *(const uint2*)&outw[row][0];  // broadcast read
            const unsigned int w = (t16 & 8) ? bits.y : bits.x;
            const int sh = (t16 & 7) * 4;
            float4 sv;
            sv.x = (float)((w >> (sh + 0)) & 1u);
            sv.y = (float)((w >> (sh + 1)) & 1u);
            sv.z = (float)((w >> (sh + 2)) & 1u);
            sv.w = (float)((w >> (sh + 3)) & 1u);
            __builtin_nontemporal_store(
                *reinterpret_cast<f4_nt*>(&sv),
                reinterpret_cast<f4_nt*>(&ov[gq + c * NV + it * 4 * (T_LEN / 4)]));
        }
    };

    // prologue: chunks 0 and 1 in flight; wait chunk 0 only (counted)
    if (wid == 1) {
        issue(0, 0);
        issue(1, 1);
        asm volatile("s_waitcnt vmcnt(16)");   // chunk 0 landed, 1 flying
    }
    BARRIER();

    int km3 = 0;   // k % 3
    #pragma unroll 1
    for (int k = 0; k < NCHUNK; ++k) {
        // ---- phase A ----
        if (wid == 0) {
            b0 = 0; b1 = 0;
            const float4* ib = (const float4*)inbuf[km3];
            #pragma unroll
            for (int g = 0; g < NV; ++g) {
                const float4 v = ib[cbase + (g ^ swl)];  // ds_read_b128
                const int t = 4 * g;
                if (t < 32) {
                    step(v.x, 1u << (t + 0), b0);
                    step(v.y, 1u << (t + 1), b0);
                    step(v.z, 1u << (t + 2), b0);
                    step(v.w, 1u << (t + 3), b0);
                } else {
                    step(v.x, 1u << (t - 32), b1);
                    step(v.y, 1u << (t - 31), b1);
                    step(v.z, 1u << (t - 30), b1);
                    step(v.w, 1u << (t - 29), b1);
                }
            }
        } else if (wid == 2) {
            if (k > 0) drain(k - 1);          // bits published in k-1's B
        }
        BARRIER();  // store's outw reads done; compute's ib reads done
        // ---- phase B ----
        if (wid == 0) {
            *(uint2*)&outw[lane][0] = make_uint2(b0, b1);
        } else if (wid == 1) {
            int nb = km3 + 2; if (nb >= 3) nb -= 3;
            if (k + 2 < NCHUNK) {
                issue(k + 2, nb);             // into buffer compute just freed
                asm volatile("s_waitcnt vmcnt(16)");  // chunk k+1 landed
            } else {
                asm volatile("s_waitcnt vmcnt(0)");   // tail: drain the rest
            }
        }
        BARRIER();  // bits(k) visible to store; inbuf[(k+1)%3] ready
        ++km3; if (km3 == 3) km3 = 0;
    }
    if (wid == 2) drain(NCHUNK - 1);
}

extern "C" void kernel_launch(void* const* d_in, const int* in_sizes, int n_in,
                              void* d_out, int out_size, void* d_ws, size_t ws_size,
                              hipStream_t stream) {
    const float* x    = (const float*)d_in[0];
    const float* beta = (const float*)d_in[1];
    const float* p    = (const float*)d_in[2];
    const float* b    = (const float*)d_in[3];
    float* out        = (float*)d_out;

    const int BN = 64 * 1024;  // rows
    snn_fwd<<<dim3(BN / ROWS), dim3(192), 0, stream>>>(x, beta, p, b, out);
}